// Round 1
// 371.280 us; speedup vs baseline: 1.0177x; 1.0177x over previous
//
#include <hip/hip_runtime.h>
#include <cmath>

// GHM-C two-stage loss, single data pass.
// loss = (1/N) * sum_b beta_b * sum_ce[b],  beta_b = 1/clip(cnt_b*nonempty, 1e-4)
//
// R5: 16-lanes-per-row, zero LDS staging, DPP reductions.
// R4 was latency-bound: single-wave blocks w/ 16.9KB LDS -> 2 waves/SIMD, and
// the stage->LDS->compute chain serialized against HBM latency (~1.8 TB/s).
// Now: lane l of a wave loads float4 #l of a contiguous 1KiB chunk (4 rows,
// perfectly coalesced, straight to VGPRs). Row max/sum reduced across the
// 16-lane group with DPP (quad_perm + row_ror) -- pure VALU, no ds pipe
// (R3's shuffle chain was the ds-pipe latency trap). x[row][t] already lives
// in lane quad==t>>2 -> component select, no gather. LDS = 120B histogram
// only -> 8 waves/SIMD (32/CU), grid 2048x256 = exactly full occupancy.
// Next-iteration global loads prefetched before current compute.

#define BINS 10
#define MAIN_BLOCKS 2048

// DPP cross-lane move within 16-lane rows. CTRL: quad_perm/row_ror encodings.
template <int CTRL>
__device__ __forceinline__ float dpp_f(float x) {
    int r = __builtin_amdgcn_update_dpp(0, __builtin_bit_cast(int, x),
                                        CTRL, 0xF, 0xF, true);
    return __builtin_bit_cast(float, r);
}
#define DPP_XOR1 0xB1   // quad_perm [1,0,3,2]
#define DPP_XOR2 0x4E   // quad_perm [2,3,0,1]
#define DPP_ROR4 0x124  // row_ror:4
#define DPP_ROR8 0x128  // row_ror:8

__global__ __launch_bounds__(256) void ghmc_main_kernel(
    const float* __restrict__ x,
    const int* __restrict__ target,
    const float* __restrict__ weight,
    const int* __restrict__ stage_p,
    double* __restrict__ part_ce,        // [BINS * MAIN_BLOCKS], bin-major
    unsigned int* __restrict__ part_cnt, // [BINS * MAIN_BLOCKS]
    int N)
{
    __shared__ double       s_ce[BINS];
    __shared__ unsigned int s_cnt[BINS];

    const int tid = threadIdx.x;
    if (tid < BINS) { s_ce[tid] = 0.0; s_cnt[tid] = 0u; }
    __syncthreads();

    const int stage = *stage_p;
    const float4* __restrict__ x4 = (const float4*)x;
    const unsigned nquads = (unsigned)N >> 2;         // 4 rows per wave-iter
    const unsigned lane   = (unsigned)tid & 63u;
    const unsigned sub    = lane >> 4;                // row within quad (0..3)
    const unsigned quad   = lane & 15u;               // float4 slot in row
    const unsigned gw     = blockIdx.x * 4u + ((unsigned)tid >> 6);
    const unsigned NW     = MAIN_BLOCKS * 4u;         // total waves

    unsigned cnt9 = 0;
    double   ce9  = 0.0;

    unsigned q = gw;
    if (q < nquads) {
        float4 v = x4[(size_t)q * 64 + lane];         // 1 KiB coalesced
        int    t = target[q * 4u + sub];              // 16B, broadcast in L1
        for (;;) {
            const unsigned qn = q + NW;
            const bool more = qn < nquads;
            float4 vn; int tn;
            if (more) {                               // prefetch next chunk
                vn = x4[(size_t)qn * 64 + lane];
                tn = target[qn * 4u + sub];
            }

            // ---- row max: in-lane 4, then 16-lane DPP butterfly (exact) ----
            float m = fmaxf(fmaxf(v.x, v.y), fmaxf(v.z, v.w));
            m = fmaxf(m, dpp_f<DPP_XOR1>(m));
            m = fmaxf(m, dpp_f<DPP_XOR2>(m));
            m = fmaxf(m, dpp_f<DPP_ROR4>(m));
            m = fmaxf(m, dpp_f<DPP_ROR8>(m));

            // ---- row sum of exp(v - m) ----
            float e0 = expf(v.x - m), e1 = expf(v.y - m);
            float e2 = expf(v.z - m), e3 = expf(v.w - m);
            float s = (e0 + e1) + (e2 + e3);
            s += dpp_f<DPP_ROR4>(s);
            s += dpp_f<DPP_ROR8>(s);
            s += dpp_f<DPP_XOR1>(s);
            s += dpp_f<DPP_XOR2>(s);

            // ---- tail: lane holding x[row][t] finishes the row ----
            if (quad == (unsigned)(t >> 2)) {
                const int c = t & 3;
                float vt = (c & 1) ? ((c & 2) ? v.w : v.y)
                                   : ((c & 2) ? v.z : v.x);
                float log_pt = (vt - m) - logf(s);    // fp32 mirrors reference
                float w  = (stage == 1) ? 1.0f : weight[t];
                float ce = -(w * log_pt);
                float g  = fabsf(expf(log_pt) - 1.0f);
                int b = (int)floorf(g * 9.9999f);     // BINS - EPS_BIN in fp32
                b = b < 0 ? 0 : (b > 9 ? 9 : b);
                if (b == 9) {
                    cnt9++;
                    ce9 += (double)ce;
                } else {
                    atomicAdd(&s_cnt[b], 1u);         // LDS atomic, rare (~1%)
                    atomicAdd(&s_ce[b], (double)ce);
                }
            }

            if (!more) break;
            v = vn; t = tn; q = qn;
        }
    }

    // once per wave: reduce the dominant bin, one LDS atomic per wave
    #pragma unroll
    for (int off = 32; off > 0; off >>= 1) {
        cnt9 += __shfl_xor(cnt9, off, 64);
        ce9  += __shfl_xor(ce9, off, 64);
    }
    if (lane == 0) {
        atomicAdd(&s_cnt[9], cnt9);
        atomicAdd(&s_ce[9], ce9);
    }
    __syncthreads();

    if (tid < BINS) {
        part_ce [tid * MAIN_BLOCKS + blockIdx.x] = s_ce[tid];
        part_cnt[tid * MAIN_BLOCKS + blockIdx.x] = s_cnt[tid];
    }
}

__global__ __launch_bounds__(1024) void ghmc_final_kernel(
    const double* __restrict__ part_ce,
    const unsigned int* __restrict__ part_cnt,
    float* __restrict__ out, int N)
{
    __shared__ double       s_ce[BINS];
    __shared__ unsigned int s_cnt[BINS];
    if (threadIdx.x < BINS) { s_ce[threadIdx.x] = 0.0; s_cnt[threadIdx.x] = 0u; }
    __syncthreads();

    #pragma unroll
    for (int b = 0; b < BINS; b++) {
        double ce = 0.0; unsigned int cnt = 0u;
        for (int k = threadIdx.x; k < MAIN_BLOCKS; k += 1024) {  // coalesced
            ce  += part_ce [b * MAIN_BLOCKS + k];
            cnt += part_cnt[b * MAIN_BLOCKS + k];
        }
        #pragma unroll
        for (int off = 32; off > 0; off >>= 1) {
            ce  += __shfl_xor(ce, off, 64);
            cnt += __shfl_xor(cnt, off, 64);
        }
        if ((threadIdx.x & 63) == 0) {
            atomicAdd(&s_ce[b], ce);
            atomicAdd(&s_cnt[b], cnt);
        }
    }
    __syncthreads();

    if (threadIdx.x == 0) {
        int nonempty = 0;
        #pragma unroll
        for (int b = 0; b < BINS; b++) nonempty += (s_cnt[b] > 0u) ? 1 : 0;
        double total = 0.0;
        #pragma unroll
        for (int b = 0; b < BINS; b++) {
            float gd = (float)s_cnt[b] * (float)nonempty;  // exact ints < 2^24
            gd = fmaxf(gd, 1e-4f);
            total += s_ce[b] / (double)gd;
        }
        out[0] = (float)(total / (double)N);
    }
}

extern "C" void kernel_launch(void* const* d_in, const int* in_sizes, int n_in,
                              void* d_out, int out_size, void* d_ws, size_t ws_size,
                              hipStream_t stream) {
    const float* x       = (const float*)d_in[0];
    const int* target    = (const int*)d_in[1];
    const float* weight  = (const float*)d_in[2];
    const int* stage_p   = (const int*)d_in[3];
    const int N = in_sizes[1];          // rows; C == 64, N % 256 == 0 assumed

    double* part_ce = (double*)d_ws;                       // 160 KiB
    unsigned int* part_cnt = (unsigned int*)(part_ce + BINS * MAIN_BLOCKS);

    // every partial slot is overwritten by the main kernel -> no memset needed
    ghmc_main_kernel<<<MAIN_BLOCKS, 256, 0, stream>>>(x, target, weight, stage_p,
                                                      part_ce, part_cnt, N);
    ghmc_final_kernel<<<1, 1024, 0, stream>>>(part_ce, part_cnt, (float*)d_out, N);
}